// Round 1
// baseline (303.063 us; speedup 1.0000x reference)
//
#include <hip/hip_runtime.h>

typedef unsigned short u16;
typedef unsigned short u16x8 __attribute__((ext_vector_type(8), may_alias));
typedef __bf16 bf16x8 __attribute__((ext_vector_type(8), may_alias));
typedef float f32x4 __attribute__((ext_vector_type(4), may_alias));

__device__ __forceinline__ u16 f2bf(float f) {
    unsigned u = __builtin_bit_cast(unsigned, f);
    u += 0x7fffu + ((u >> 16) & 1u);
    return (u16)(u >> 16);
}

// ---------------- fp32 -> bf16 elementwise ----------------
__global__ __launch_bounds__(256) void cvt_f32_bf16_k(const float* __restrict__ in,
                                                      u16* __restrict__ out, int n8) {
    int i = blockIdx.x * 256 + threadIdx.x;
    if (i >= n8) return;
    float4 a = reinterpret_cast<const float4*>(in)[2 * i];
    float4 c = reinterpret_cast<const float4*>(in)[2 * i + 1];
    u16x8 o;
    o[0] = f2bf(a.x); o[1] = f2bf(a.y); o[2] = f2bf(a.z); o[3] = f2bf(a.w);
    o[4] = f2bf(c.x); o[5] = f2bf(c.y); o[6] = f2bf(c.z); o[7] = f2bf(c.w);
    reinterpret_cast<u16x8*>(out)[i] = o;
}

// ---------------- fp32 [R][C] -> bf16 [C][R] transpose ----------------
__global__ __launch_bounds__(256) void tr_f32_bf16_k(const float* __restrict__ in,
                                                     u16* __restrict__ out, int R, int C) {
    __shared__ u16 t[64][73];
    int tc = C >> 6;
    int r0 = (blockIdx.x / tc) << 6, c0 = (blockIdx.x % tc) << 6;
    int lr = threadIdx.x >> 2;
    int lc = (threadIdx.x & 3) << 4;
    const float* src = in + (size_t)(r0 + lr) * C + c0 + lc;
#pragma unroll
    for (int j = 0; j < 16; j += 4) {
        float4 v = *reinterpret_cast<const float4*>(src + j);
        t[lr][lc + j + 0] = f2bf(v.x);
        t[lr][lc + j + 1] = f2bf(v.y);
        t[lr][lc + j + 2] = f2bf(v.z);
        t[lr][lc + j + 3] = f2bf(v.w);
    }
    __syncthreads();
    u16x8 o0, o1;
#pragma unroll
    for (int j = 0; j < 8; j++) { o0[j] = t[lc + j][lr]; o1[j] = t[lc + 8 + j][lr]; }
    u16* dst = out + (size_t)(c0 + lr) * R + r0 + lc;
    *reinterpret_cast<u16x8*>(dst) = o0;
    *reinterpret_cast<u16x8*>(dst + 8) = o1;
}

// ---------------- V section of qkv -> Vt[bh][64][2048] ----------------
__global__ __launch_bounds__(256) void tr_v_k(const u16* __restrict__ qkv,
                                              u16* __restrict__ Vt) {
    __shared__ u16 t[64][73];
    int bh = blockIdx.x >> 5;
    int n0 = (blockIdx.x & 31) << 6;
    int b = bh >> 4, h = bh & 15;
    int lr = threadIdx.x >> 2;
    int lc = (threadIdx.x & 3) << 4;
    const u16* src = qkv + (size_t)(b * 2048 + n0 + lr) * 3072 + 2048 + h * 64 + lc;
    u16x8 v0 = *reinterpret_cast<const u16x8*>(src);
    u16x8 v1 = *reinterpret_cast<const u16x8*>(src + 8);
#pragma unroll
    for (int j = 0; j < 8; j++) { t[lr][lc + j] = v0[j]; t[lr][lc + 8 + j] = v1[j]; }
    __syncthreads();
    u16x8 o0, o1;
#pragma unroll
    for (int j = 0; j < 8; j++) { o0[j] = t[lc + j][lr]; o1[j] = t[lc + 8 + j][lr]; }
    u16* dst = Vt + (size_t)(bh * 64 + lr) * 2048 + n0 + lc;
    *reinterpret_cast<u16x8*>(dst) = o0;
    *reinterpret_cast<u16x8*>(dst + 8) = o1;
}

// ---------------- bf16 GEMM: C[M][N] = A[M][K] * Bt[N][K]^T + bias ----------------
template <int OUTF32>
__global__ __launch_bounds__(256) void gemm_bt_k(const u16* __restrict__ A,
                                                 const u16* __restrict__ Bt,
                                                 const float* __restrict__ bias,
                                                 u16* __restrict__ Cb,
                                                 float* __restrict__ Cf,
                                                 int M, int N, int K) {
    __shared__ u16 As[128 * 64];
    __shared__ u16 Bs[128 * 64];
    const int tid = threadIdx.x;
    const int l = tid & 63, w = tid >> 6;
    const int wm = w >> 1, wn = w & 1;
    const int l16 = l & 15, lg = l >> 4;
    const int tc = N >> 7;
    const int bm = blockIdx.x / tc, bn = blockIdx.x % tc;
    const u16* Ab = A + (size_t)(bm << 7) * K;
    const u16* Bb = Bt + (size_t)(bn << 7) * K;

    f32x4 acc[4][4];
#pragma unroll
    for (int mi = 0; mi < 4; mi++)
#pragma unroll
        for (int ni = 0; ni < 4; ni++)
#pragma unroll
            for (int q = 0; q < 4; q++) acc[mi][ni][q] = 0.f;

    u16x8 av[4], bv[4];
#pragma unroll
    for (int i = 0; i < 4; i++) {
        int s = tid + (i << 8);
        av[i] = *reinterpret_cast<const u16x8*>(Ab + (size_t)(s >> 3) * K + ((s & 7) << 3));
        bv[i] = *reinterpret_cast<const u16x8*>(Bb + (size_t)(s >> 3) * K + ((s & 7) << 3));
    }
    for (int k0 = 0; k0 < K; k0 += 64) {
        __syncthreads();
#pragma unroll
        for (int i = 0; i < 4; i++) {
            int s = tid + (i << 8);
            *reinterpret_cast<u16x8*>(&As[s << 3]) = av[i];
            *reinterpret_cast<u16x8*>(&Bs[s << 3]) = bv[i];
        }
        __syncthreads();
        if (k0 + 64 < K) {
#pragma unroll
            for (int i = 0; i < 4; i++) {
                int s = tid + (i << 8);
                av[i] = *reinterpret_cast<const u16x8*>(Ab + (size_t)(s >> 3) * K + (k0 + 64) + ((s & 7) << 3));
                bv[i] = *reinterpret_cast<const u16x8*>(Bb + (size_t)(s >> 3) * K + (k0 + 64) + ((s & 7) << 3));
            }
        }
#pragma unroll
        for (int kk = 0; kk < 2; kk++) {
            bf16x8 af[4], bfr[4];
#pragma unroll
            for (int mi = 0; mi < 4; mi++)
                af[mi] = *reinterpret_cast<const bf16x8*>(
                    &As[((wm << 6) + (mi << 4) + l16) * 64 + (kk << 5) + (lg << 3)]);
#pragma unroll
            for (int ni = 0; ni < 4; ni++)
                bfr[ni] = *reinterpret_cast<const bf16x8*>(
                    &Bs[((wn << 6) + (ni << 4) + l16) * 64 + (kk << 5) + (lg << 3)]);
#pragma unroll
            for (int mi = 0; mi < 4; mi++)
#pragma unroll
                for (int ni = 0; ni < 4; ni++)
                    acc[mi][ni] = __builtin_amdgcn_mfma_f32_16x16x32_bf16(af[mi], bfr[ni], acc[mi][ni], 0, 0, 0);
        }
    }
    const int rb = (bm << 7) + (wm << 6), cb = (bn << 7) + (wn << 6);
#pragma unroll
    for (int ni = 0; ni < 4; ni++) {
        int col = cb + (ni << 4) + l16;
        float bb = bias[col];
#pragma unroll
        for (int mi = 0; mi < 4; mi++)
#pragma unroll
            for (int r = 0; r < 4; r++) {
                int row = rb + (mi << 4) + (lg << 2) + r;
                float v = acc[mi][ni][r] + bb;
                if constexpr (OUTF32) Cf[(size_t)row * N + col] = v;
                else Cb[(size_t)row * N + col] = f2bf(v);
            }
    }
}

// ---------------- flash attention: 1 wave = 32 q rows ----------------
__global__ __launch_bounds__(256) void attn_k(const u16* __restrict__ qkv,
                                              const u16* __restrict__ Vt,
                                              u16* __restrict__ Y) {
    __shared__ u16 P_lds[4][32 * 40];
    const int tid = threadIdx.x;
    const int l = tid & 63, w = tid >> 6;
    const int l16 = l & 15, lg = l >> 4;
    const int wid = blockIdx.x * 4 + w;
    const int qt = 63 - (wid >> 6);     // 32-row q tile, heavy tiles first
    const int bh = wid & 63;
    const int b = bh >> 4, h = bh & 15;

    const u16* Qb = qkv + (size_t)(b * 2048) * 3072 + h * 64;
    const u16* Kb = qkv + (size_t)(b * 2048) * 3072 + 1024 + h * 64;
    const u16* Vb = Vt + (size_t)(bh * 64) * 2048;
    u16* pl = &P_lds[w][0];

    bf16x8 qf[2][2];
#pragma unroll
    for (int mi = 0; mi < 2; mi++) {
        size_t roff = (size_t)(qt * 32 + mi * 16 + l16) * 3072;
#pragma unroll
        for (int kk = 0; kk < 2; kk++)
            qf[mi][kk] = *reinterpret_cast<const bf16x8*>(Qb + roff + kk * 32 + lg * 8);
    }

    f32x4 o[2][4];
    float m_i[2][4], l_i[2][4];
#pragma unroll
    for (int mi = 0; mi < 2; mi++)
#pragma unroll
        for (int r = 0; r < 4; r++) {
            m_i[mi][r] = -1e30f;
            l_i[mi][r] = 0.f;
#pragma unroll
            for (int n = 0; n < 4; n++) o[mi][n][r] = 0.f;
        }

    const int ntiles = qt + 1;
    for (int it = 0; it < ntiles; it++) {
        const int kv0 = it * 32;
        bf16x8 kf[2][2];
#pragma unroll
        for (int t = 0; t < 2; t++) {
            size_t roff = (size_t)(kv0 + t * 16 + l16) * 3072;
#pragma unroll
            for (int kk = 0; kk < 2; kk++)
                kf[t][kk] = *reinterpret_cast<const bf16x8*>(Kb + roff + kk * 32 + lg * 8);
        }
        float p[2][2][4];
#pragma unroll
        for (int mi = 0; mi < 2; mi++) {
#pragma unroll
            for (int t = 0; t < 2; t++) {
                f32x4 s;
                s[0] = s[1] = s[2] = s[3] = 0.f;
                s = __builtin_amdgcn_mfma_f32_16x16x32_bf16(qf[mi][0], kf[t][0], s, 0, 0, 0);
                s = __builtin_amdgcn_mfma_f32_16x16x32_bf16(qf[mi][1], kf[t][1], s, 0, 0, 0);
                const int colq = kv0 + t * 16 + l16;
                const int rowq = qt * 32 + mi * 16 + lg * 4;
#pragma unroll
                for (int r = 0; r < 4; r++)
                    p[mi][t][r] = (colq <= rowq + r) ? s[r] * 0.125f : -1e30f;
            }
        }
#pragma unroll
        for (int mi = 0; mi < 2; mi++) {
            float mloc[4], rs[4], alpha[4];
#pragma unroll
            for (int r = 0; r < 4; r++) mloc[r] = fmaxf(p[mi][0][r], p[mi][1][r]);
#pragma unroll
            for (int off = 1; off < 16; off <<= 1)
#pragma unroll
                for (int r = 0; r < 4; r++)
                    mloc[r] = fmaxf(mloc[r], __shfl_xor(mloc[r], off, 64));
#pragma unroll
            for (int r = 0; r < 4; r++) {
                float mn = fmaxf(m_i[mi][r], mloc[r]);
                alpha[r] = __expf(m_i[mi][r] - mn);
                m_i[mi][r] = mn;
                p[mi][0][r] = __expf(p[mi][0][r] - mn);
                p[mi][1][r] = __expf(p[mi][1][r] - mn);
                rs[r] = p[mi][0][r] + p[mi][1][r];
            }
#pragma unroll
            for (int off = 1; off < 16; off <<= 1)
#pragma unroll
                for (int r = 0; r < 4; r++) rs[r] += __shfl_xor(rs[r], off, 64);
#pragma unroll
            for (int r = 0; r < 4; r++) l_i[mi][r] = l_i[mi][r] * alpha[r] + rs[r];
#pragma unroll
            for (int n = 0; n < 4; n++)
#pragma unroll
                for (int r = 0; r < 4; r++) o[mi][n][r] *= alpha[r];
#pragma unroll
            for (int t = 0; t < 2; t++)
#pragma unroll
                for (int r = 0; r < 4; r++)
                    pl[(mi * 16 + lg * 4 + r) * 40 + t * 16 + l16] = f2bf(p[mi][t][r]);
        }
        bf16x8 pa[2];
#pragma unroll
        for (int mi = 0; mi < 2; mi++)
            pa[mi] = *reinterpret_cast<const bf16x8*>(pl + (mi * 16 + l16) * 40 + lg * 8);
#pragma unroll
        for (int n = 0; n < 4; n++) {
            bf16x8 vf = *reinterpret_cast<const bf16x8*>(Vb + (size_t)(n * 16 + l16) * 2048 + kv0 + lg * 8);
#pragma unroll
            for (int mi = 0; mi < 2; mi++)
                o[mi][n] = __builtin_amdgcn_mfma_f32_16x16x32_bf16(pa[mi], vf, o[mi][n], 0, 0, 0);
        }
    }
#pragma unroll
    for (int mi = 0; mi < 2; mi++) {
        const size_t rbase = (size_t)(b * 2048 + qt * 32 + mi * 16 + lg * 4);
#pragma unroll
        for (int n = 0; n < 4; n++)
#pragma unroll
            for (int r = 0; r < 4; r++)
                Y[(rbase + r) * 1024 + h * 64 + n * 16 + l16] = f2bf(o[mi][n][r] / l_i[mi][r]);
    }
}

extern "C" void kernel_launch(void* const* d_in, const int* in_sizes, int n_in,
                              void* d_out, int out_size, void* d_ws, size_t ws_size,
                              hipStream_t stream) {
    const float* x     = (const float*)d_in[0];
    const float* w_qkv = (const float*)d_in[1];
    const float* b_qkv = (const float*)d_in[2];
    const float* w_o   = (const float*)d_in[3];
    const float* b_o   = (const float*)d_in[4];
    float* out = (float*)d_out;

    // ws layout (u16 units): qkv[8192*3072] | xb_y[8192*1024] | wqT[3072*1024] | woT[1024*1024] | vt[64*64*2048]
    u16* ws   = (u16*)d_ws;
    u16* qkv  = ws;
    u16* xb_y = ws + 25165824;   // x as bf16, later reused for attention output Y
    u16* wqT  = ws + 33554432;
    u16* woT  = ws + 36700160;
    u16* vt   = ws + 37748736;   // end: 46137344 u16 = 92.3 MB

    cvt_f32_bf16_k<<<4096, 256, 0, stream>>>(x, xb_y, 1048576);
    tr_f32_bf16_k<<<768, 256, 0, stream>>>(w_qkv, wqT, 1024, 3072);
    tr_f32_bf16_k<<<256, 256, 0, stream>>>(w_o, woT, 1024, 1024);
    gemm_bt_k<0><<<1536, 256, 0, stream>>>(xb_y, wqT, b_qkv, qkv, nullptr, 8192, 3072, 1024);
    tr_v_k<<<2048, 256, 0, stream>>>(qkv, vt);
    attn_k<<<1024, 256, 0, stream>>>(qkv, vt, xb_y);
    gemm_bt_k<1><<<512, 256, 0, stream>>>(xb_y, woT, b_o, nullptr, out, 8192, 1024, 1024);
}

// Round 2
// 252.103 us; speedup vs baseline: 1.2021x; 1.2021x over previous
//
#include <hip/hip_runtime.h>

typedef unsigned short u16;
typedef unsigned short u16x4 __attribute__((ext_vector_type(4), may_alias));
typedef unsigned short u16x8 __attribute__((ext_vector_type(8), may_alias));
typedef __bf16 bf16x8 __attribute__((ext_vector_type(8), may_alias));
typedef float f32x4 __attribute__((ext_vector_type(4), may_alias));

typedef __attribute__((address_space(1))) void gvoid_t;
typedef __attribute__((address_space(3))) void lvoid_t;

__device__ __forceinline__ void gld16(const void* g, void* l) {
    __builtin_amdgcn_global_load_lds((gvoid_t*)g, (lvoid_t*)l, 16, 0, 0);
}

__device__ __forceinline__ u16 f2bf(float f) {
    unsigned u = __builtin_bit_cast(unsigned, f);
    u += 0x7fffu + ((u >> 16) & 1u);
    return (u16)(u >> 16);
}

#define KSCALE 0.18033688011112042f  /* 0.125 * log2(e) */

// ---------------- fp32 -> bf16 elementwise ----------------
__global__ __launch_bounds__(256) void cvt_f32_bf16_k(const float* __restrict__ in,
                                                      u16* __restrict__ out, int n8) {
    int i = blockIdx.x * 256 + threadIdx.x;
    if (i >= n8) return;
    float4 a = reinterpret_cast<const float4*>(in)[2 * i];
    float4 c = reinterpret_cast<const float4*>(in)[2 * i + 1];
    u16x8 o;
    o[0] = f2bf(a.x); o[1] = f2bf(a.y); o[2] = f2bf(a.z); o[3] = f2bf(a.w);
    o[4] = f2bf(c.x); o[5] = f2bf(c.y); o[6] = f2bf(c.z); o[7] = f2bf(c.w);
    reinterpret_cast<u16x8*>(out)[i] = o;
}

// ---------------- fp32 [R][C] -> bf16 [C][R] transpose ----------------
__global__ __launch_bounds__(256) void tr_f32_bf16_k(const float* __restrict__ in,
                                                     u16* __restrict__ out, int R, int C) {
    __shared__ u16 t[64][73];
    int tc = C >> 6;
    int r0 = (blockIdx.x / tc) << 6, c0 = (blockIdx.x % tc) << 6;
    int lr = threadIdx.x >> 2;
    int lc = (threadIdx.x & 3) << 4;
    const float* src = in + (size_t)(r0 + lr) * C + c0 + lc;
#pragma unroll
    for (int j = 0; j < 16; j += 4) {
        float4 v = *reinterpret_cast<const float4*>(src + j);
        t[lr][lc + j + 0] = f2bf(v.x);
        t[lr][lc + j + 1] = f2bf(v.y);
        t[lr][lc + j + 2] = f2bf(v.z);
        t[lr][lc + j + 3] = f2bf(v.w);
    }
    __syncthreads();
    u16x8 o0, o1;
#pragma unroll
    for (int j = 0; j < 8; j++) { o0[j] = t[lc + j][lr]; o1[j] = t[lc + 8 + j][lr]; }
    u16* dst = out + (size_t)(c0 + lr) * R + r0 + lc;
    *reinterpret_cast<u16x8*>(dst) = o0;
    *reinterpret_cast<u16x8*>(dst + 8) = o1;
}

// ---------------- bf16 GEMM: C = A[M][K] * Bt[N][K]^T + bias ----------------
// MODE 0: N==3072, scatter epilogue -> Qp/Kp(scaled)/Vt(transposed) packed per head
// MODE 1: f32 output Cf[M][N]
template <int MODE>
__global__ __launch_bounds__(256) void gemm_bt_k(const u16* __restrict__ A,
                                                 const u16* __restrict__ Bt,
                                                 const float* __restrict__ bias,
                                                 u16* __restrict__ Qp, u16* __restrict__ Kp,
                                                 u16* __restrict__ Vt,
                                                 float* __restrict__ Cf,
                                                 int M, int N, int K) {
    __shared__ u16 As[2][128 * 64];
    __shared__ u16 Bs[2][128 * 64];
    const int tid = threadIdx.x;
    const int l = tid & 63, w = tid >> 6;
    const int wm = w >> 1, wn = w & 1;
    const int l16 = l & 15, lg = l >> 4;
    const int tc = N >> 7;
    const int bm = blockIdx.x / tc, bn = blockIdx.x % tc;
    const u16* Ab = A + (size_t)(bm << 7) * K;
    const u16* Bb = Bt + (size_t)(bn << 7) * K;

    f32x4 acc[4][4];
#pragma unroll
    for (int mi = 0; mi < 4; mi++)
#pragma unroll
        for (int ni = 0; ni < 4; ni++)
#pragma unroll
            for (int q = 0; q < 4; q++) acc[mi][ni][q] = 0.f;

    auto stage = [&](int buf, int k0) {
#pragma unroll
        for (int i = 0; i < 4; i++) {
            int s = tid + (i << 8);
            int ub = ((i << 8) + (w << 6)) << 3;   // wave-uniform LDS elem offset
            gld16(Ab + (size_t)(s >> 3) * K + k0 + ((s & 7) << 3), &As[buf][ub]);
            gld16(Bb + (size_t)(s >> 3) * K + k0 + ((s & 7) << 3), &Bs[buf][ub]);
        }
    };

    stage(0, 0);
    int cur = 0;
    for (int k0 = 0; k0 < K; k0 += 64) {
        __syncthreads();                 // drains vmcnt -> tile `cur` ready; buf cur^1 free
        if (k0 + 64 < K) stage(cur ^ 1, k0 + 64);
        const u16* Asc = As[cur];
        const u16* Bsc = Bs[cur];
#pragma unroll
        for (int kk = 0; kk < 2; kk++) {
            bf16x8 af[4], bfr[4];
#pragma unroll
            for (int mi = 0; mi < 4; mi++)
                af[mi] = *reinterpret_cast<const bf16x8*>(
                    &Asc[((wm << 6) + (mi << 4) + l16) * 64 + (kk << 5) + (lg << 3)]);
#pragma unroll
            for (int ni = 0; ni < 4; ni++)
                bfr[ni] = *reinterpret_cast<const bf16x8*>(
                    &Bsc[((wn << 6) + (ni << 4) + l16) * 64 + (kk << 5) + (lg << 3)]);
#pragma unroll
            for (int mi = 0; mi < 4; mi++)
#pragma unroll
                for (int ni = 0; ni < 4; ni++)
                    acc[mi][ni] = __builtin_amdgcn_mfma_f32_16x16x32_bf16(af[mi], bfr[ni], acc[mi][ni], 0, 0, 0);
        }
        cur ^= 1;
    }

    const int rb = (bm << 7) + (wm << 6), cb = (bn << 7) + (wn << 6);
    if constexpr (MODE == 0) {
        const int sec = cb >> 10;   // 0=Q 1=K 2=V, uniform per block (128 | 1024)
#pragma unroll
        for (int ni = 0; ni < 4; ni++) {
            const int col = cb + (ni << 4) + l16;
            const float bb = bias[col];
            const int d = col & 1023, h = d >> 6, dh = d & 63;
#pragma unroll
            for (int mi = 0; mi < 4; mi++) {
                const int row0 = rb + (mi << 4) + (lg << 2);
                const int bidx = row0 >> 11, n0 = row0 & 2047;
                const size_t base = (size_t)(bidx * 16 + h) * 131072;
                if (sec == 0) {
#pragma unroll
                    for (int r = 0; r < 4; r++)
                        Qp[base + (size_t)(n0 + r) * 64 + dh] = f2bf(acc[mi][ni][r] + bb);
                } else if (sec == 1) {
#pragma unroll
                    for (int r = 0; r < 4; r++)
                        Kp[base + (size_t)(n0 + r) * 64 + dh] = f2bf((acc[mi][ni][r] + bb) * KSCALE);
                } else {
                    u16x4 pk;
#pragma unroll
                    for (int r = 0; r < 4; r++) pk[r] = f2bf(acc[mi][ni][r] + bb);
                    *reinterpret_cast<u16x4*>(&Vt[base + (size_t)dh * 2048 + n0]) = pk;
                }
            }
        }
    } else {
#pragma unroll
        for (int ni = 0; ni < 4; ni++) {
            const int col = cb + (ni << 4) + l16;
            const float bb = bias[col];
#pragma unroll
            for (int mi = 0; mi < 4; mi++)
#pragma unroll
                for (int r = 0; r < 4; r++) {
                    const int row = rb + (mi << 4) + (lg << 2) + r;
                    Cf[(size_t)row * N + col] = acc[mi][ni][r] + bb;
                }
        }
    }
}

// ---------------- flash attention: 1 wave = 32 q rows, KVBLK=64 ----------------
__global__ __launch_bounds__(256) void attn_k(const u16* __restrict__ Qp,
                                              const u16* __restrict__ Kp,
                                              const u16* __restrict__ Vt,
                                              u16* __restrict__ Y) {
    __shared__ u16 P_lds[4][32 * 72];
    const int tid = threadIdx.x;
    const int l = tid & 63, w = tid >> 6;
    const int l16 = l & 15, lg = l >> 4;
    const int wid = blockIdx.x * 4 + w;
    const int qt = 63 - (wid >> 6);     // heavy q-tiles first
    const int bh = wid & 63;
    const u16* Qb = Qp + (size_t)bh * 131072;
    const u16* Kb = Kp + (size_t)bh * 131072;
    const u16* Vb = Vt + (size_t)bh * 131072;
    u16* pl = &P_lds[w][0];

    bf16x8 qf[2][2];
#pragma unroll
    for (int mi = 0; mi < 2; mi++)
#pragma unroll
        for (int kk = 0; kk < 2; kk++)
            qf[mi][kk] = *reinterpret_cast<const bf16x8*>(
                Qb + (size_t)(qt * 32 + mi * 16 + l16) * 64 + kk * 32 + lg * 8);

    f32x4 o[2][4];
    float m_i[2][4], l_i[2][4];
#pragma unroll
    for (int mi = 0; mi < 2; mi++)
#pragma unroll
        for (int r = 0; r < 4; r++) {
            m_i[mi][r] = -1e30f;
            l_i[mi][r] = 0.f;
#pragma unroll
            for (int n = 0; n < 4; n++) o[mi][n][r] = 0.f;
        }

    const int nt = (qt >> 1) + 1;
    for (int it = 0; it < nt; it++) {
        const int kv0 = it << 6;
        const bool last = (it == nt - 1);
        bf16x8 kf[4][2];
#pragma unroll
        for (int t = 0; t < 4; t++)
#pragma unroll
            for (int kk = 0; kk < 2; kk++)
                kf[t][kk] = *reinterpret_cast<const bf16x8*>(
                    Kb + (size_t)(kv0 + t * 16 + l16) * 64 + kk * 32 + lg * 8);

#pragma unroll
        for (int mi = 0; mi < 2; mi++) {
            float s4[4][4];
            const int rowq = qt * 32 + mi * 16 + lg * 4;
#pragma unroll
            for (int t = 0; t < 4; t++) {
                f32x4 s;
                s[0] = s[1] = s[2] = s[3] = 0.f;
                s = __builtin_amdgcn_mfma_f32_16x16x32_bf16(qf[mi][0], kf[t][0], s, 0, 0, 0);
                s = __builtin_amdgcn_mfma_f32_16x16x32_bf16(qf[mi][1], kf[t][1], s, 0, 0, 0);
                if (last) {
                    const int colq = kv0 + t * 16 + l16;
#pragma unroll
                    for (int r = 0; r < 4; r++)
                        s4[t][r] = (colq <= rowq + r) ? s[r] : -1e30f;
                } else {
#pragma unroll
                    for (int r = 0; r < 4; r++) s4[t][r] = s[r];
                }
            }
            float mloc[4];
#pragma unroll
            for (int r = 0; r < 4; r++)
                mloc[r] = fmaxf(fmaxf(s4[0][r], s4[1][r]), fmaxf(s4[2][r], s4[3][r]));
#pragma unroll
            for (int off = 1; off < 16; off <<= 1)
#pragma unroll
                for (int r = 0; r < 4; r++)
                    mloc[r] = fmaxf(mloc[r], __shfl_xor(mloc[r], off, 64));
            float growth = fmaxf(fmaxf(mloc[0] - m_i[mi][0], mloc[1] - m_i[mi][1]),
                                 fmaxf(mloc[2] - m_i[mi][2], mloc[3] - m_i[mi][3]));
            if (!__all(growth <= 8.0f)) {        // defer-max: rescale only on real growth
#pragma unroll
                for (int r = 0; r < 4; r++) {
                    float mn = fmaxf(m_i[mi][r], mloc[r]);
                    float al = __builtin_amdgcn_exp2f(m_i[mi][r] - mn);
                    m_i[mi][r] = mn;
                    l_i[mi][r] *= al;
#pragma unroll
                    for (int n = 0; n < 4; n++) o[mi][n][r] *= al;
                }
            }
            float rs[4];
#pragma unroll
            for (int t = 0; t < 4; t++)
#pragma unroll
                for (int r = 0; r < 4; r++)
                    s4[t][r] = __builtin_amdgcn_exp2f(s4[t][r] - m_i[mi][r]);
#pragma unroll
            for (int r = 0; r < 4; r++)
                rs[r] = (s4[0][r] + s4[1][r]) + (s4[2][r] + s4[3][r]);
#pragma unroll
            for (int off = 1; off < 16; off <<= 1)
#pragma unroll
                for (int r = 0; r < 4; r++) rs[r] += __shfl_xor(rs[r], off, 64);
#pragma unroll
            for (int r = 0; r < 4; r++) l_i[mi][r] += rs[r];
#pragma unroll
            for (int t = 0; t < 4; t++)
#pragma unroll
                for (int r = 0; r < 4; r++)
                    pl[(mi * 16 + lg * 4 + r) * 72 + t * 16 + l16] = f2bf(s4[t][r]);
        }
        bf16x8 pa[2][2];
#pragma unroll
        for (int mi = 0; mi < 2; mi++)
#pragma unroll
            for (int kk2 = 0; kk2 < 2; kk2++)
                pa[mi][kk2] = *reinterpret_cast<const bf16x8*>(
                    pl + (mi * 16 + l16) * 72 + kk2 * 32 + lg * 8);
#pragma unroll
        for (int n = 0; n < 4; n++) {
            const u16* vr = Vb + (size_t)(n * 16 + l16) * 2048 + kv0 + lg * 8;
            bf16x8 v0 = *reinterpret_cast<const bf16x8*>(vr);
            bf16x8 v1 = *reinterpret_cast<const bf16x8*>(vr + 32);
#pragma unroll
            for (int mi = 0; mi < 2; mi++) {
                o[mi][n] = __builtin_amdgcn_mfma_f32_16x16x32_bf16(pa[mi][0], v0, o[mi][n], 0, 0, 0);
                o[mi][n] = __builtin_amdgcn_mfma_f32_16x16x32_bf16(pa[mi][1], v1, o[mi][n], 0, 0, 0);
            }
        }
    }
    const int b = bh >> 4, h = bh & 15;
#pragma unroll
    for (int mi = 0; mi < 2; mi++) {
        const size_t rbase = (size_t)(b * 2048 + qt * 32 + mi * 16 + lg * 4);
#pragma unroll
        for (int r = 0; r < 4; r++) {
            const float inv = 1.0f / l_i[mi][r];
#pragma unroll
            for (int n = 0; n < 4; n++)
                Y[(rbase + r) * 1024 + h * 64 + n * 16 + l16] = f2bf(o[mi][n][r] * inv);
        }
    }
}

extern "C" void kernel_launch(void* const* d_in, const int* in_sizes, int n_in,
                              void* d_out, int out_size, void* d_ws, size_t ws_size,
                              hipStream_t stream) {
    const float* x     = (const float*)d_in[0];
    const float* w_qkv = (const float*)d_in[1];
    const float* b_qkv = (const float*)d_in[2];
    const float* w_o   = (const float*)d_in[3];
    const float* b_o   = (const float*)d_in[4];
    float* out = (float*)d_out;

    // ws layout (u16 units):
    u16* ws  = (u16*)d_ws;
    u16* xb  = ws;                 // [8192][1024] x bf16; reused as attention output Y
    u16* wqT = ws + 8388608;       // [3072][1024]
    u16* woT = ws + 11534336;      // [1024][1024]
    u16* Qp  = ws + 12582912;      // [64 bh][2048][64]
    u16* Kp  = ws + 20971520;      // [64 bh][2048][64] (pre-scaled by 0.125*log2e)
    u16* Vt  = ws + 29360128;      // [64 bh][64][2048]
    // end: 37748736 u16 = 75.5 MB

    cvt_f32_bf16_k<<<4096, 256, 0, stream>>>(x, xb, 1048576);
    tr_f32_bf16_k<<<768, 256, 0, stream>>>(w_qkv, wqT, 1024, 3072);
    tr_f32_bf16_k<<<256, 256, 0, stream>>>(w_o, woT, 1024, 1024);
    gemm_bt_k<0><<<1536, 256, 0, stream>>>(xb, wqT, b_qkv, Qp, Kp, Vt, nullptr, 8192, 3072, 1024);
    attn_k<<<1024, 256, 0, stream>>>(Qp, Kp, Vt, xb);
    gemm_bt_k<1><<<512, 256, 0, stream>>>(xb, woT, b_o, nullptr, nullptr, nullptr, out, 8192, 1024, 1024);
}